// Round 14
// baseline (83.449 us; speedup 1.0000x reference)
//
#include <hip/hip_runtime.h>

// ThinPlateSpline: out = K_query @ rbf_weights + P_query @ poly_coeffs
//   K_ij = r*ln(r), r = ||u_i - c_j|| (d=3)
//   kk = sqrt(r2) * log2(r2) * C, C = 0.5*ln2 folded into staged weights.
//
// R14: single-variable change vs R13 (best, kernel ~31.5us). Model: trans
// unit is effectively CU-shared ~8cyc/wave64-op -> 2 trans/pair = ~27us
// floor that every structure since R7 has sat on. This round halves trans
// ops: hw v_log stays, hw v_sqrt -> packed Newton soft-sqrt (scalar
// bit-hack seed + v_pk_mul/v_pk_fma Newton, +4.5 cyc/pair-wave VALU, which
// has headroom in the packed base). Numerics of this approx validated R6.
// Everything else identical to R13: pre-duplicated packed LDS records,
// QPT=4 = 2 v2f groups, BLK=256 (4 waves = 4 n-splits), JCHUNK=128,
// grid (64,32) = 8 blocks/CU, in-block reduction, coalesced atomics.

typedef float v2f __attribute__((ext_vector_type(2)));
typedef float v4f __attribute__((ext_vector_type(4)));

#define BLK 256
#define NS 4            // waves per block = in-block n-splits
#define QPT 4           // queries per lane = 2 packed groups
#define QPB 256         // queries per block = 64 * QPT
#define JCHUNK 128      // j per block
#define JW (JCHUNK / NS)

__global__ __launch_bounds__(BLK, 8) void tps_kernel(
    const float* __restrict__ u,     // (batch, 3)
    const float* __restrict__ cp,    // (n, 3)
    const float* __restrict__ w,     // (n, 3)
    const float* __restrict__ poly,  // (4, 3)
    float* __restrict__ out,         // (batch, 3)
    int batch, int n)
{
    __shared__ v4f s_a4[JCHUNK * 2];
    __shared__ v4f s_b4[JCHUNK * 2];
    __shared__ float s_red[NS][QPB * 3];   // per-wave partials (12 KB)

    const float C = 0.34657359027997264f;  // 0.5 * ln(2)

    const int tid = threadIdx.x;
    const int j0 = blockIdx.y * JCHUNK;

    if (tid < JCHUNK) {  // stage + transform + duplicate this 128-j slice
        const int g = j0 + tid;
        const float cx = cp[g * 3 + 0], cy = cp[g * 3 + 1], cz = cp[g * 3 + 2];
        const float c2 = fmaf(cx, cx, fmaf(cy, cy, cz * cz));
        const float wx = C * w[g * 3 + 0];
        const float wy = C * w[g * 3 + 1];
        const float wz = C * w[g * 3 + 2];
        s_a4[tid * 2 + 0] = (v4f){-2.f * cx, -2.f * cx, -2.f * cy, -2.f * cy};
        s_a4[tid * 2 + 1] = (v4f){-2.f * cz, -2.f * cz, c2, c2};
        s_b4[tid * 2 + 0] = (v4f){wx, wx, wy, wy};
        s_b4[tid * 2 + 1] = (v4f){wz, wz, 0.f, 0.f};
    }
    __syncthreads();

    const int lane = tid & 63;
    const int wv   = tid >> 6;    // 0..3 = n-split

    v2f uxv[2], uyv[2], uzv[2], usqv[2];
    v2f axv[2], ayv[2], azv[2];
#pragma unroll
    for (int g = 0; g < 2; ++g) {
        const int qa = blockIdx.x * QPB + (2 * g + 0) * 64 + lane;
        const int qb = blockIdx.x * QPB + (2 * g + 1) * 64 + lane;
        uxv[g] = (v2f){u[qa * 3 + 0], u[qb * 3 + 0]};
        uyv[g] = (v2f){u[qa * 3 + 1], u[qb * 3 + 1]};
        uzv[g] = (v2f){u[qa * 3 + 2], u[qb * 3 + 2]};
        usqv[g] = __builtin_elementwise_fma(uxv[g], uxv[g],
                  __builtin_elementwise_fma(uyv[g], uyv[g], uzv[g] * uzv[g]));
        axv[g] = (v2f){0.f, 0.f};
        ayv[g] = (v2f){0.f, 0.f};
        azv[g] = (v2f){0.f, 0.f};
    }

    if (blockIdx.y == 0 && wv == 0) {  // polynomial term exactly once
#pragma unroll
        for (int g = 0; g < 2; ++g) {
            axv[g] = poly[0] + uxv[g] * poly[3] + uyv[g] * poly[6] + uzv[g] * poly[9];
            ayv[g] = poly[1] + uxv[g] * poly[4] + uyv[g] * poly[7] + uzv[g] * poly[10];
            azv[g] = poly[2] + uxv[g] * poly[5] + uyv[g] * poly[8] + uzv[g] * poly[11];
        }
    }

    const int jlo = wv * JW;
#pragma unroll 2
    for (int j = jlo; j < jlo + JW; ++j) {
        const v4f A0 = s_a4[j * 2 + 0];  // {ax,ax,ay,ay}
        const v4f A1 = s_a4[j * 2 + 1];  // {az,az,c2,c2}
        const v4f B0 = s_b4[j * 2 + 0];  // {wx,wx,wy,wy}
        const v4f B1 = s_b4[j * 2 + 1];  // {wz,wz,0,0}
        const v2f m2x = A0.xy, m2y = A0.zw, m2z = A1.xy, c2v = A1.zw;
        const v2f wxv = B0.xy, wyv = B0.zw, wzv = B1.xy;
#pragma unroll
        for (int g = 0; g < 2; ++g) {
            v2f r2 = __builtin_elementwise_fma(m2x, uxv[g],
                     __builtin_elementwise_fma(m2y, uyv[g],
                     __builtin_elementwise_fma(m2z, uzv[g], c2v + usqv[g])));
            r2 = __builtin_elementwise_max(r2, (v2f){1e-30f, 1e-30f});

            // packed soft sqrt: scalar bit-hack seed + packed Newton
            v2f y = {__int_as_float(0x5f3759df - (__float_as_int(r2.x) >> 1)),
                     __int_as_float(0x5f3759df - (__float_as_int(r2.y) >> 1))};
            const v2f h  = r2 * (v2f){-0.5f, -0.5f};          // pk_mul
            const v2f t  = __builtin_elementwise_fma(h, y * y,
                                      (v2f){1.5f, 1.5f});      // pk_mul+pk_fma
            y = y * t;                                         // pk_mul
            const v2f sq = r2 * y;                             // pk_mul

            // hw log only (1 trans/pair instead of 2)
            const v2f lg = {__builtin_amdgcn_logf(r2.x),
                            __builtin_amdgcn_logf(r2.y)};
            const v2f kk = sq * lg;                            // pk_mul
            axv[g] = __builtin_elementwise_fma(kk, wxv, axv[g]);
            ayv[g] = __builtin_elementwise_fma(kk, wyv, ayv[g]);
            azv[g] = __builtin_elementwise_fma(kk, wzv, azv[g]);
        }
    }

    // In-block reduction across the 4 n-split waves.
#pragma unroll
    for (int g = 0; g < 2; ++g) {
        const int ba = ((2 * g + 0) * 64 + lane) * 3;
        const int bb = ((2 * g + 1) * 64 + lane) * 3;
        s_red[wv][ba + 0] = axv[g].x;  s_red[wv][bb + 0] = axv[g].y;
        s_red[wv][ba + 1] = ayv[g].x;  s_red[wv][bb + 1] = ayv[g].y;
        s_red[wv][ba + 2] = azv[g].x;  s_red[wv][bb + 2] = azv[g].y;
    }
    __syncthreads();

    for (int v = tid; v < QPB * 3; v += BLK) {
        float s = s_red[0][v] + s_red[1][v] + s_red[2][v] + s_red[3][v];
        atomicAdd(&out[(size_t)blockIdx.x * (QPB * 3) + v], s);
    }
}

extern "C" void kernel_launch(void* const* d_in, const int* in_sizes, int n_in,
                              void* d_out, int out_size, void* d_ws, size_t ws_size,
                              hipStream_t stream) {
    const float* u    = (const float*)d_in[0];  // (batch,3)
    const float* cp   = (const float*)d_in[1];  // (n,3)
    const float* w    = (const float*)d_in[2];  // (n,3)
    const float* poly = (const float*)d_in[3];  // (4,3)
    float* out = (float*)d_out;

    const int batch = in_sizes[0] / 3;  // 16384
    const int n     = in_sizes[1] / 3;  // 4096

    hipMemsetAsync(d_out, 0, (size_t)out_size * sizeof(float), stream);

    dim3 block(BLK);
    dim3 grid(batch / QPB, n / JCHUNK);  // (64, 32) = 2048 blocks
    tps_kernel<<<grid, block, 0, stream>>>(u, cp, w, poly, out, batch, n);
}

// Round 15
// 80.877 us; speedup vs baseline: 1.0318x; 1.0318x over previous
//
#include <hip/hip_runtime.h>

// ThinPlateSpline: out = K_query @ rbf_weights + P_query @ poly_coeffs
//   K_ij = r*ln(r), r = ||u_i - c_j|| (d=3)
//   kk = sqrt(r2) * log2(r2) * C, C = 0.5*ln2 folded into staged weights.
//
// R15: single-variable test vs R13 (best, 78.9 total / kernel ~31.5us).
// R14 proved hw trans is ~free (removing v_sqrt saved 0); the plateau is
// VALU-issue. R13's packed model predicts ~10us but measured 31.5 --
// suspect __builtin_elementwise_* SCALARIZED the v2f ops. This round forces
// VOP3P via inline asm: v_pk_add_f32 / v_pk_fma_f32 / v_pk_mul_f32 (CDNA2+;
// no v_pk_max_f32 exists -> guard stays 2 scalar v_max). Everything else
// identical to R13: pre-duplicated packed LDS records, QPT=4 = 2 v2f
// groups, BLK=256 (4 waves = 4 n-splits), JCHUNK=128, grid (64,32) =
// 8 blocks/CU, in-block LDS reduction, coalesced atomics across grid.y.

typedef float v2f __attribute__((ext_vector_type(2)));
typedef float v4f __attribute__((ext_vector_type(4)));

#define BLK 256
#define NS 4            // waves per block = in-block n-splits
#define QPT 4           // queries per lane = 2 packed groups
#define QPB 256         // queries per block = 64 * QPT
#define JCHUNK 128      // j per block
#define JW (JCHUNK / NS)

__global__ __launch_bounds__(BLK, 8) void tps_kernel(
    const float* __restrict__ u,     // (batch, 3)
    const float* __restrict__ cp,    // (n, 3)
    const float* __restrict__ w,     // (n, 3)
    const float* __restrict__ poly,  // (4, 3)
    float* __restrict__ out,         // (batch, 3)
    int batch, int n)
{
    __shared__ v4f s_a4[JCHUNK * 2];
    __shared__ v4f s_b4[JCHUNK * 2];
    __shared__ float s_red[NS][QPB * 3];   // per-wave partials (12 KB)

    const float C = 0.34657359027997264f;  // 0.5 * ln(2)

    const int tid = threadIdx.x;
    const int j0 = blockIdx.y * JCHUNK;

    if (tid < JCHUNK) {  // stage + transform + duplicate this 128-j slice
        const int g = j0 + tid;
        const float cx = cp[g * 3 + 0], cy = cp[g * 3 + 1], cz = cp[g * 3 + 2];
        const float c2 = fmaf(cx, cx, fmaf(cy, cy, cz * cz));
        const float wx = C * w[g * 3 + 0];
        const float wy = C * w[g * 3 + 1];
        const float wz = C * w[g * 3 + 2];
        s_a4[tid * 2 + 0] = (v4f){-2.f * cx, -2.f * cx, -2.f * cy, -2.f * cy};
        s_a4[tid * 2 + 1] = (v4f){-2.f * cz, -2.f * cz, c2, c2};
        s_b4[tid * 2 + 0] = (v4f){wx, wx, wy, wy};
        s_b4[tid * 2 + 1] = (v4f){wz, wz, 0.f, 0.f};
    }
    __syncthreads();

    const int lane = tid & 63;
    const int wv   = tid >> 6;    // 0..3 = n-split

    v2f uxv[2], uyv[2], uzv[2], usqv[2];
    v2f axv[2], ayv[2], azv[2];
#pragma unroll
    for (int g = 0; g < 2; ++g) {
        const int qa = blockIdx.x * QPB + (2 * g + 0) * 64 + lane;
        const int qb = blockIdx.x * QPB + (2 * g + 1) * 64 + lane;
        uxv[g] = (v2f){u[qa * 3 + 0], u[qb * 3 + 0]};
        uyv[g] = (v2f){u[qa * 3 + 1], u[qb * 3 + 1]};
        uzv[g] = (v2f){u[qa * 3 + 2], u[qb * 3 + 2]};
        usqv[g] = __builtin_elementwise_fma(uxv[g], uxv[g],
                  __builtin_elementwise_fma(uyv[g], uyv[g], uzv[g] * uzv[g]));
        axv[g] = (v2f){0.f, 0.f};
        ayv[g] = (v2f){0.f, 0.f};
        azv[g] = (v2f){0.f, 0.f};
    }

    if (blockIdx.y == 0 && wv == 0) {  // polynomial term exactly once
#pragma unroll
        for (int g = 0; g < 2; ++g) {
            axv[g] = poly[0] + uxv[g] * poly[3] + uyv[g] * poly[6] + uzv[g] * poly[9];
            ayv[g] = poly[1] + uxv[g] * poly[4] + uyv[g] * poly[7] + uzv[g] * poly[10];
            azv[g] = poly[2] + uxv[g] * poly[5] + uyv[g] * poly[8] + uzv[g] * poly[11];
        }
    }

    const int jlo = wv * JW;
#pragma unroll 2
    for (int j = jlo; j < jlo + JW; ++j) {
        const v4f A0 = s_a4[j * 2 + 0];  // {ax,ax,ay,ay}
        const v4f A1 = s_a4[j * 2 + 1];  // {az,az,c2,c2}
        const v4f B0 = s_b4[j * 2 + 0];  // {wx,wx,wy,wy}
        const v4f B1 = s_b4[j * 2 + 1];  // {wz,wz,0,0}
        const v2f m2x = A0.xy, m2y = A0.zw, m2z = A1.xy, c2v = A1.zw;
        const v2f wxv = B0.xy, wyv = B0.zw, wzv = B1.xy;
#pragma unroll
        for (int g = 0; g < 2; ++g) {
            // ---- forced VOP3P core (9 packed instrs per 2 pairs) ----
            v2f r2;
            asm("v_pk_add_f32 %0, %1, %2"
                : "=v"(r2) : "v"(c2v), "v"(usqv[g]));
            asm("v_pk_fma_f32 %0, %1, %2, %0"
                : "+v"(r2) : "v"(m2z), "v"(uzv[g]));
            asm("v_pk_fma_f32 %0, %1, %2, %0"
                : "+v"(r2) : "v"(m2y), "v"(uyv[g]));
            asm("v_pk_fma_f32 %0, %1, %2, %0"
                : "+v"(r2) : "v"(m2x), "v"(uxv[g]));
            // guard (no v_pk_max_f32 on CDNA): 2 scalar v_max_f32
            r2.x = fmaxf(r2.x, 1e-30f);
            r2.y = fmaxf(r2.y, 1e-30f);
            // hw trans (proven ~free, co-issued)
            const v2f sq = {__builtin_amdgcn_sqrtf(r2.x),
                            __builtin_amdgcn_sqrtf(r2.y)};
            const v2f lg = {__builtin_amdgcn_logf(r2.x),
                            __builtin_amdgcn_logf(r2.y)};
            v2f kk;
            asm("v_pk_mul_f32 %0, %1, %2"
                : "=v"(kk) : "v"(sq), "v"(lg));
            asm("v_pk_fma_f32 %0, %1, %2, %0"
                : "+v"(axv[g]) : "v"(kk), "v"(wxv));
            asm("v_pk_fma_f32 %0, %1, %2, %0"
                : "+v"(ayv[g]) : "v"(kk), "v"(wyv));
            asm("v_pk_fma_f32 %0, %1, %2, %0"
                : "+v"(azv[g]) : "v"(kk), "v"(wzv));
        }
    }

    // In-block reduction across the 4 n-split waves.
#pragma unroll
    for (int g = 0; g < 2; ++g) {
        const int ba = ((2 * g + 0) * 64 + lane) * 3;
        const int bb = ((2 * g + 1) * 64 + lane) * 3;
        s_red[wv][ba + 0] = axv[g].x;  s_red[wv][bb + 0] = axv[g].y;
        s_red[wv][ba + 1] = ayv[g].x;  s_red[wv][bb + 1] = ayv[g].y;
        s_red[wv][ba + 2] = azv[g].x;  s_red[wv][bb + 2] = azv[g].y;
    }
    __syncthreads();

    for (int v = tid; v < QPB * 3; v += BLK) {
        float s = s_red[0][v] + s_red[1][v] + s_red[2][v] + s_red[3][v];
        atomicAdd(&out[(size_t)blockIdx.x * (QPB * 3) + v], s);
    }
}

extern "C" void kernel_launch(void* const* d_in, const int* in_sizes, int n_in,
                              void* d_out, int out_size, void* d_ws, size_t ws_size,
                              hipStream_t stream) {
    const float* u    = (const float*)d_in[0];  // (batch,3)
    const float* cp   = (const float*)d_in[1];  // (n,3)
    const float* w    = (const float*)d_in[2];  // (n,3)
    const float* poly = (const float*)d_in[3];  // (4,3)
    float* out = (float*)d_out;

    const int batch = in_sizes[0] / 3;  // 16384
    const int n     = in_sizes[1] / 3;  // 4096

    hipMemsetAsync(d_out, 0, (size_t)out_size * sizeof(float), stream);

    dim3 block(BLK);
    dim3 grid(batch / QPB, n / JCHUNK);  // (64, 32) = 2048 blocks
    tps_kernel<<<grid, block, 0, stream>>>(u, cp, w, poly, out, batch, n);
}